// Round 2
// baseline (242.464 us; speedup 1.0000x reference)
//
#include <hip/hip_runtime.h>

#define B_ 64
#define H_ 32
#define DN 512
#define DR 64
#define BS 128
#define SB 64
#define MAXKV 4096
#define LOG2E 1.44269504088896340736f
#define SCALE_ (1.0f/24.0f)   // 1/sqrt(576)
#define NEG_INF -1e30f

typedef float    f32x4 __attribute__((ext_vector_type(4)));
typedef _Float16 f16x4 __attribute__((ext_vector_type(4)));

#define MFMA16 __builtin_amdgcn_mfma_f32_16x16x16f16

__device__ __forceinline__ f16x4 cvt4(f32x4 a) {
  f16x4 r;
  r[0] = (_Float16)a[0]; r[1] = (_Float16)a[1];
  r[2] = (_Float16)a[2]; r[3] = (_Float16)a[3];
  return r;
}

// Kernel 1: per (b, chunk) flash-decode partial. 4 waves; per 64-key
// sub-block each wave owns one 16-key S-tile (S^T = K·Q^T via 16x16x16
// f16 MFMA, classic fragment layout) and a 128-dim slice for PV.
// V is staged TRANSPOSED in LDS so PV's B-fragment is a contiguous load.
__global__ __launch_bounds__(256) void mla_chunk(
    const float* __restrict__ qn, const float* __restrict__ qr,
    const float* __restrict__ kvn, const float* __restrict__ kvr,
    const int* __restrict__ btab, const int* __restrict__ kseq,
    float* __restrict__ po, float* __restrict__ ml,
    const int nc, const int chunk)
{
  const int bc = blockIdx.x;
  const int b = bc / nc, c = bc - b * nc;
  const int klen = kseq[b];
  const int kbase = c * chunk;
  if (kbase >= klen) return;
  const int nvalid = min(chunk, klen - kbase);
  const int nsb = (nvalid + SB - 1) / SB;

  const int tid = threadIdx.x;
  const int w = tid >> 6, l = tid & 63, l15 = l & 15, lg = l >> 4;
  const int kd = lg * 4;

  __shared__ _Float16 Vt[DN][SB + 4];       // V^T: [dim][key], 69.6 KB
  __shared__ _Float16 Plds[H_][72];         // P: [head][key-local]
  __shared__ float m_tab[4][H_], l_tab[4][H_];
  __shared__ float Mnew_s[H_], fact_s[H_], Mrun[H_], Lrun[H_];

  if (tid < H_) { Mrun[tid] = NEG_INF; Lrun[tid] = 0.f; }

  f32x4 acc[2][8];
  #pragma unroll
  for (int i = 0; i < 2; ++i)
    #pragma unroll
    for (int j = 0; j < 8; ++j) acc[i][j] = (f32x4){0.f, 0.f, 0.f, 0.f};

  // Q row pointers: B-fragment lane holds Q[head = l15 (+16)][k-dims]
  const float* q0  = qn + ((size_t)b * H_ + l15) * DN;
  const float* q1  = qn + ((size_t)b * H_ + 16 + l15) * DN;
  const float* qr0 = qr + ((size_t)b * H_ + l15) * DR;
  const float* qr1 = qr + ((size_t)b * H_ + 16 + l15) * DR;

  __syncthreads();

  for (int sb = 0; sb < nsb; ++sb) {
    // ---- Phase A: S^T tile = K·Q^T over 576 dims; stage V^T in LDS ----
    const int kb  = kbase + sb * SB + w * 16;
    const int blk = btab[b * 32 + (kb >> 7)];
    const int row = (kb & (BS - 1)) + l15;
    const float* kn_ = kvn + ((size_t)blk * BS + row) * DN;
    const float* kr_ = kvr + ((size_t)blk * BS + row) * DR;
    const int klr = w * 16 + l15;           // key-local index in sub-block

    f32x4 s0 = {0.f,0.f,0.f,0.f}, s1 = {0.f,0.f,0.f,0.f};
    #pragma unroll 4
    for (int d0 = 0; d0 < 32; ++d0) {
      const int dd = d0 * 16 + kd;          // A-frag: K[kb+l15][dd..dd+3]
      f16x4 af = cvt4(*(const f32x4*)(kn_ + dd));
      Vt[dd + 0][klr] = af[0];
      Vt[dd + 1][klr] = af[1];
      Vt[dd + 2][klr] = af[2];
      Vt[dd + 3][klr] = af[3];
      s0 = MFMA16(af, cvt4(*(const f32x4*)(q0 + dd)), s0, 0, 0, 0);
      s1 = MFMA16(af, cvt4(*(const f32x4*)(q1 + dd)), s1, 0, 0, 0);
    }
    #pragma unroll
    for (int d0 = 0; d0 < 4; ++d0) {        // rope dims
      const int dd = d0 * 16 + kd;
      f16x4 af = cvt4(*(const f32x4*)(kr_ + dd));
      s0 = MFMA16(af, cvt4(*(const f32x4*)(qr0 + dd)), s0, 0, 0, 0);
      s1 = MFMA16(af, cvt4(*(const f32x4*)(qr1 + dd)), s1, 0, 0, 0);
    }

    // D layout: row(key) = lg*4 + r, col(head) = l15. Scale+mask+max.
    float v0[4], v1[4];
    float mx0 = NEG_INF, mx1 = NEG_INF;
    #pragma unroll
    for (int r = 0; r < 4; ++r) {
      const bool ok = (kb + lg * 4 + r) < klen;
      v0[r] = ok ? s0[r] * SCALE_ : NEG_INF;
      v1[r] = ok ? s1[r] * SCALE_ : NEG_INF;
      mx0 = fmaxf(mx0, v0[r]); mx1 = fmaxf(mx1, v1[r]);
    }
    mx0 = fmaxf(mx0, __shfl_xor(mx0, 16)); mx0 = fmaxf(mx0, __shfl_xor(mx0, 32));
    mx1 = fmaxf(mx1, __shfl_xor(mx1, 16)); mx1 = fmaxf(mx1, __shfl_xor(mx1, 32));
    if (lg == 0) { m_tab[w][l15] = mx0; m_tab[w][16 + l15] = mx1; }
    __syncthreads();

    // ---- Phase B: combine running max per head ----
    if (tid < H_) {
      const float mp = Mrun[tid];
      float mn = fmaxf(fmaxf(m_tab[0][tid], m_tab[1][tid]),
                       fmaxf(m_tab[2][tid], m_tab[3][tid]));
      mn = fmaxf(mn, mp);
      Mnew_s[tid] = mn;
      fact_s[tid] = exp2f((mp - mn) * LOG2E);
      Mrun[tid]   = mn;
    }
    __syncthreads();

    // ---- Phase C: P = exp(s - M) -> LDS; rescale out-acc ----
    const float mn0 = Mnew_s[l15], mn1 = Mnew_s[16 + l15];
    float p0[4], p1[4];
    float ls0 = 0.f, ls1 = 0.f;
    #pragma unroll
    for (int r = 0; r < 4; ++r) {
      p0[r] = exp2f((v0[r] - mn0) * LOG2E); ls0 += p0[r];
      p1[r] = exp2f((v1[r] - mn1) * LOG2E); ls1 += p1[r];
    }
    ls0 += __shfl_xor(ls0, 16); ls0 += __shfl_xor(ls0, 32);
    ls1 += __shfl_xor(ls1, 16); ls1 += __shfl_xor(ls1, 32);
    if (lg == 0) { l_tab[w][l15] = ls0; l_tab[w][16 + l15] = ls1; }
    f16x4 pk0, pk1;
    #pragma unroll
    for (int r = 0; r < 4; ++r) { pk0[r] = (_Float16)p0[r]; pk1[r] = (_Float16)p1[r]; }
    *(f16x4*)&Plds[l15][w * 16 + kd]      = pk0;
    *(f16x4*)&Plds[16 + l15][w * 16 + kd] = pk1;
    #pragma unroll
    for (int ht = 0; ht < 2; ++ht) {
      #pragma unroll
      for (int r = 0; r < 4; ++r) {
        const float f = fact_s[ht * 16 + lg * 4 + r];
        #pragma unroll
        for (int dt = 0; dt < 8; ++dt) acc[ht][dt][r] *= f;
      }
    }
    __syncthreads();

    // ---- Phase D: running denominator ----
    if (tid < H_) {
      Lrun[tid] = Lrun[tid] * fact_s[tid] +
                  (l_tab[0][tid] + l_tab[1][tid]) + (l_tab[2][tid] + l_tab[3][tid]);
    }

    // ---- Phase E: PV. Wave w owns dims [w*128, w*128+128). ----
    #pragma unroll
    for (int ks = 0; ks < 4; ++ks) {
      f16x4 pa0 = *(const f16x4*)&Plds[l15][ks * 16 + kd];
      f16x4 pa1 = *(const f16x4*)&Plds[16 + l15][ks * 16 + kd];
      #pragma unroll
      for (int dt = 0; dt < 8; ++dt) {
        // B-frag: V[key = ks*16 + lg*4 + i][dim = w*128 + dt*16 + l15]
        f16x4 bv = *(const f16x4*)&Vt[w * 128 + dt * 16 + l15][ks * 16 + kd];
        acc[0][dt] = MFMA16(pa0, bv, acc[0][dt], 0, 0, 0);
        acc[1][dt] = MFMA16(pa1, bv, acc[1][dt], 0, 0, 0);
      }
    }
    __syncthreads();   // protect Vt/Plds for next sub-block
  }

  // ---- write partials: O (unnormalized), m, l ----
  float* pop = po + ((size_t)(b * nc + c)) * H_ * DN;
  #pragma unroll
  for (int ht = 0; ht < 2; ++ht)
    #pragma unroll
    for (int dt = 0; dt < 8; ++dt)
      #pragma unroll
      for (int r = 0; r < 4; ++r)
        pop[(size_t)(ht * 16 + lg * 4 + r) * DN + w * 128 + dt * 16 + l15] = acc[ht][dt][r];
  if (tid < H_) {
    const size_t o = ((size_t)(b * nc + c) * H_ + tid) * 2;
    ml[o] = Mrun[tid]; ml[o + 1] = Lrun[tid];
  }
}

// Kernel 2: merge chunk partials per (b,h).
__global__ __launch_bounds__(256) void mla_reduce(
    const float* __restrict__ po, const float* __restrict__ ml,
    const int* __restrict__ kseq, float* __restrict__ out,
    const int nc, const int chunk)
{
  const int bh = blockIdx.x;
  const int b = bh >> 5, h = bh & 31;
  const int klen = kseq[b];
  const int na = min(nc, (klen + chunk - 1) / chunk);
  const int tid = threadIdx.x;

  float M = NEG_INF;
  for (int c = 0; c < na; ++c)
    M = fmaxf(M, ml[((size_t)(b * nc + c) * H_ + h) * 2]);

  float s0 = 0.f, s1 = 0.f, den = 0.f;
  for (int c = 0; c < na; ++c) {
    const size_t o = ((size_t)(b * nc + c) * H_ + h) * 2;
    const float e = exp2f((ml[o] - M) * LOG2E);
    den += ml[o + 1] * e;
    const float* p = po + ((size_t)(b * nc + c) * H_ + h) * DN;
    s0 += p[tid] * e;
    s1 += p[tid + 256] * e;
  }
  const float inv = 1.f / den;
  float* op = out + ((size_t)b * H_ + h) * DN;
  op[tid]       = s0 * inv;
  op[tid + 256] = s1 * inv;
}

extern "C" void kernel_launch(void* const* d_in, const int* in_sizes, int n_in,
                              void* d_out, int out_size, void* d_ws, size_t ws_size,
                              hipStream_t stream) {
  const float* qn  = (const float*)d_in[0];
  const float* qr  = (const float*)d_in[1];
  const float* kvn = (const float*)d_in[2];
  const float* kvr = (const float*)d_in[3];
  const int*  btab = (const int*)d_in[4];
  const int*  kseq = (const int*)d_in[6];
  float* out = (float*)d_out;

  // workspace-adaptive chunk count: nc chunks of 4096/nc keys
  int nc = 8;
  while (nc > 1 && ((size_t)B_ * nc * H_ * (DN + 2) * sizeof(float)) > ws_size)
    nc >>= 1;
  const int chunk = MAXKV / nc;

  float* po = (float*)d_ws;                       // [B][nc][H][DN] f32
  float* ml = po + (size_t)B_ * nc * H_ * DN;     // [B][nc][H][2]  f32

  mla_chunk<<<B_ * nc, 256, 0, stream>>>(qn, qr, kvn, kvr, btab, kseq,
                                         po, ml, nc, chunk);
  mla_reduce<<<B_ * H_, 256, 0, stream>>>(po, ml, kseq, out, nc, chunk);
}

// Round 3
// 232.713 us; speedup vs baseline: 1.0419x; 1.0419x over previous
//
#include <hip/hip_runtime.h>

#define B_ 64
#define H_ 32
#define DN 512
#define DR 64
#define BS 128
#define SB 64
#define MAXKV 4096
#define LOG2E 1.44269504088896340736f
#define SCALE_ (1.0f/24.0f)   // 1/sqrt(576)
#define NEG_INF -1e30f

typedef float    f32x4 __attribute__((ext_vector_type(4)));
typedef _Float16 f16x4 __attribute__((ext_vector_type(4)));

#define MFMA16 __builtin_amdgcn_mfma_f32_16x16x16f16

__device__ __forceinline__ f16x4 cvt4(f32x4 a) {
  f16x4 r;
  r[0] = (_Float16)a[0]; r[1] = (_Float16)a[1];
  r[2] = (_Float16)a[2]; r[3] = (_Float16)a[3];
  return r;
}

// Kernel 1: per (b, chunk) flash-decode partial. 4 waves; per 64-key
// sub-block each wave owns one 16-key S-tile (S^T = K·Q^T, 16x16x16 f16
// MFMA) and a 128-dim slice for PV. Q held in registers (f16 fragments)
// for the whole block; K explicitly prefetched 2 iterations deep.
__global__ __launch_bounds__(256, 2) void mla_chunk(
    const float* __restrict__ qn, const float* __restrict__ qr,
    const float* __restrict__ kvn, const float* __restrict__ kvr,
    const int* __restrict__ btab, const int* __restrict__ kseq,
    float* __restrict__ po, float* __restrict__ ml,
    const int nc, const int chunk)
{
  const int bc = blockIdx.x;
  const int b = bc / nc, c = bc - b * nc;
  const int klen = kseq[b];
  const int kbase = c * chunk;
  if (kbase >= klen) return;
  const int nvalid = min(chunk, klen - kbase);
  const int nsb = (nvalid + SB - 1) / SB;

  const int tid = threadIdx.x;
  const int w = tid >> 6, l = tid & 63, l15 = l & 15, lg = l >> 4;
  const int kd = lg * 4;

  __shared__ _Float16 Vt[DN][SB + 4];       // V^T: [dim][key], 69.6 KB
  __shared__ _Float16 Plds[H_][72];         // P: [head][key-local]
  __shared__ float m_tab[4][H_], l_tab[4][H_];
  __shared__ float Mnew_s[H_], fact_s[H_], Mrun[H_], Lrun[H_];

  if (tid < H_) { Mrun[tid] = NEG_INF; Lrun[tid] = 0.f; }

  f32x4 acc[2][8];
  #pragma unroll
  for (int i = 0; i < 2; ++i)
    #pragma unroll
    for (int j = 0; j < 8; ++j) acc[i][j] = (f32x4){0.f, 0.f, 0.f, 0.f};

  // ---- Q fragments in registers, f16, loaded once per block ----
  // B-frag lane mapping (16x16x16): col = l15 (head), k = kd + i (dim).
  const float* q0  = qn + ((size_t)b * H_ + l15) * DN + kd;
  const float* q1  = qn + ((size_t)b * H_ + 16 + l15) * DN + kd;
  const float* qr0 = qr + ((size_t)b * H_ + l15) * DR + kd;
  const float* qr1 = qr + ((size_t)b * H_ + 16 + l15) * DR + kd;
  f16x4 Qn0[32], Qn1[32], Qr0v[4], Qr1v[4];
  #pragma unroll
  for (int d0 = 0; d0 < 32; ++d0) {
    Qn0[d0] = cvt4(*(const f32x4*)(q0 + d0 * 16));
    Qn1[d0] = cvt4(*(const f32x4*)(q1 + d0 * 16));
  }
  #pragma unroll
  for (int i = 0; i < 4; ++i) {
    Qr0v[i] = cvt4(*(const f32x4*)(qr0 + i * 16));
    Qr1v[i] = cvt4(*(const f32x4*)(qr1 + i * 16));
  }

  __syncthreads();

  for (int sb = 0; sb < nsb; ++sb) {
    // ---- Phase A: S^T tile = K·Q^T over 576 dims; stage V^T in LDS ----
    const int kb  = kbase + sb * SB + w * 16;
    const int blk = btab[b * 32 + (kb >> 7)];
    const int row = (kb & (BS - 1)) + l15;
    const float* kn_ = kvn + ((size_t)blk * BS + row) * DN + kd;
    const float* kr_ = kvr + ((size_t)blk * BS + row) * DR + kd;
    const int klr = w * 16 + l15;           // key-local index in sub-block

    f32x4 s0 = {0.f,0.f,0.f,0.f}, s1 = {0.f,0.f,0.f,0.f};
    // 2-deep register prefetch over 36 d0-steps (32 nope + 4 rope)
    f32x4 ka = *(const f32x4*)(kn_);
    f32x4 kb2 = *(const f32x4*)(kn_ + 16);
    #pragma unroll
    for (int d0 = 0; d0 < 36; d0 += 2) {
      f32x4 kna = ka, knb = kb2;
      if (d0 + 2 < 32) {
        kna = *(const f32x4*)(kn_ + (d0 + 2) * 16);
        knb = *(const f32x4*)(kn_ + (d0 + 3) * 16);
      } else if (d0 + 2 == 32) {
        kna = *(const f32x4*)(kr_);
        knb = *(const f32x4*)(kr_ + 16);
      } else if (d0 + 2 == 34) {
        kna = *(const f32x4*)(kr_ + 32);
        knb = *(const f32x4*)(kr_ + 48);
      }
      // process d0
      {
        f16x4 af = cvt4(ka);
        if (d0 < 32) {
          const int dd = d0 * 16 + kd;
          Vt[dd + 0][klr] = af[0]; Vt[dd + 1][klr] = af[1];
          Vt[dd + 2][klr] = af[2]; Vt[dd + 3][klr] = af[3];
          s0 = MFMA16(af, Qn0[d0], s0, 0, 0, 0);
          s1 = MFMA16(af, Qn1[d0], s1, 0, 0, 0);
        } else {
          s0 = MFMA16(af, Qr0v[d0 - 32], s0, 0, 0, 0);
          s1 = MFMA16(af, Qr1v[d0 - 32], s1, 0, 0, 0);
        }
      }
      // process d0+1
      {
        f16x4 af = cvt4(kb2);
        if (d0 + 1 < 32) {
          const int dd = (d0 + 1) * 16 + kd;
          Vt[dd + 0][klr] = af[0]; Vt[dd + 1][klr] = af[1];
          Vt[dd + 2][klr] = af[2]; Vt[dd + 3][klr] = af[3];
          s0 = MFMA16(af, Qn0[d0 + 1], s0, 0, 0, 0);
          s1 = MFMA16(af, Qn1[d0 + 1], s1, 0, 0, 0);
        } else {
          s0 = MFMA16(af, Qr0v[d0 + 1 - 32], s0, 0, 0, 0);
          s1 = MFMA16(af, Qr1v[d0 + 1 - 32], s1, 0, 0, 0);
        }
      }
      ka = kna; kb2 = knb;
    }

    // D layout: row(key) = lg*4 + r, col(head) = l15. Scale+mask+max.
    float v0[4], v1[4];
    float mx0 = NEG_INF, mx1 = NEG_INF;
    #pragma unroll
    for (int r = 0; r < 4; ++r) {
      const bool ok = (kb + lg * 4 + r) < klen;
      v0[r] = ok ? s0[r] * SCALE_ : NEG_INF;
      v1[r] = ok ? s1[r] * SCALE_ : NEG_INF;
      mx0 = fmaxf(mx0, v0[r]); mx1 = fmaxf(mx1, v1[r]);
    }
    mx0 = fmaxf(mx0, __shfl_xor(mx0, 16)); mx0 = fmaxf(mx0, __shfl_xor(mx0, 32));
    mx1 = fmaxf(mx1, __shfl_xor(mx1, 16)); mx1 = fmaxf(mx1, __shfl_xor(mx1, 32));
    if (lg == 0) { m_tab[w][l15] = mx0; m_tab[w][16 + l15] = mx1; }
    __syncthreads();

    // ---- Phase B: combine running max per head ----
    if (tid < H_) {
      const float mp = Mrun[tid];
      float mn = fmaxf(fmaxf(m_tab[0][tid], m_tab[1][tid]),
                       fmaxf(m_tab[2][tid], m_tab[3][tid]));
      mn = fmaxf(mn, mp);
      Mnew_s[tid] = mn;
      fact_s[tid] = exp2f((mp - mn) * LOG2E);
      Mrun[tid]   = mn;
    }
    __syncthreads();

    // ---- Phase C: P = exp(s - M) -> LDS; rescale out-acc ----
    const float mn0 = Mnew_s[l15], mn1 = Mnew_s[16 + l15];
    float p0[4], p1[4];
    float ls0 = 0.f, ls1 = 0.f;
    #pragma unroll
    for (int r = 0; r < 4; ++r) {
      p0[r] = exp2f((v0[r] - mn0) * LOG2E); ls0 += p0[r];
      p1[r] = exp2f((v1[r] - mn1) * LOG2E); ls1 += p1[r];
    }
    ls0 += __shfl_xor(ls0, 16); ls0 += __shfl_xor(ls0, 32);
    ls1 += __shfl_xor(ls1, 16); ls1 += __shfl_xor(ls1, 32);
    if (lg == 0) { l_tab[w][l15] = ls0; l_tab[w][16 + l15] = ls1; }
    f16x4 pk0, pk1;
    #pragma unroll
    for (int r = 0; r < 4; ++r) { pk0[r] = (_Float16)p0[r]; pk1[r] = (_Float16)p1[r]; }
    *(f16x4*)&Plds[l15][w * 16 + kd]      = pk0;
    *(f16x4*)&Plds[16 + l15][w * 16 + kd] = pk1;
    #pragma unroll
    for (int ht = 0; ht < 2; ++ht) {
      #pragma unroll
      for (int r = 0; r < 4; ++r) {
        const float f = fact_s[ht * 16 + lg * 4 + r];
        #pragma unroll
        for (int dt = 0; dt < 8; ++dt) acc[ht][dt][r] *= f;
      }
    }
    __syncthreads();

    // ---- Phase D: running denominator ----
    if (tid < H_) {
      Lrun[tid] = Lrun[tid] * fact_s[tid] +
                  (l_tab[0][tid] + l_tab[1][tid]) + (l_tab[2][tid] + l_tab[3][tid]);
    }

    // ---- Phase E: PV. Wave w owns dims [w*128, w*128+128). ----
    #pragma unroll
    for (int ks = 0; ks < 4; ++ks) {
      f16x4 pa0 = *(const f16x4*)&Plds[l15][ks * 16 + kd];
      f16x4 pa1 = *(const f16x4*)&Plds[16 + l15][ks * 16 + kd];
      #pragma unroll
      for (int dt = 0; dt < 8; ++dt) {
        // B-frag: V[key = ks*16 + lg*4 + i][dim = w*128 + dt*16 + l15]
        f16x4 bv = *(const f16x4*)&Vt[w * 128 + dt * 16 + l15][ks * 16 + kd];
        acc[0][dt] = MFMA16(pa0, bv, acc[0][dt], 0, 0, 0);
        acc[1][dt] = MFMA16(pa1, bv, acc[1][dt], 0, 0, 0);
      }
    }
    __syncthreads();   // protect Vt/Plds for next sub-block
  }

  // ---- write partials: O (unnormalized), m, l ----
  float* pop = po + ((size_t)(b * nc + c)) * H_ * DN;
  #pragma unroll
  for (int ht = 0; ht < 2; ++ht)
    #pragma unroll
    for (int dt = 0; dt < 8; ++dt)
      #pragma unroll
      for (int r = 0; r < 4; ++r)
        pop[(size_t)(ht * 16 + lg * 4 + r) * DN + w * 128 + dt * 16 + l15] = acc[ht][dt][r];
  if (tid < H_) {
    const size_t o = ((size_t)(b * nc + c) * H_ + tid) * 2;
    ml[o] = Mrun[tid]; ml[o + 1] = Lrun[tid];
  }
}

// Kernel 2: merge chunk partials per (b,h).
__global__ __launch_bounds__(256) void mla_reduce(
    const float* __restrict__ po, const float* __restrict__ ml,
    const int* __restrict__ kseq, float* __restrict__ out,
    const int nc, const int chunk)
{
  const int bh = blockIdx.x;
  const int b = bh >> 5, h = bh & 31;
  const int klen = kseq[b];
  const int na = min(nc, (klen + chunk - 1) / chunk);
  const int tid = threadIdx.x;

  float M = NEG_INF;
  for (int c = 0; c < na; ++c)
    M = fmaxf(M, ml[((size_t)(b * nc + c) * H_ + h) * 2]);

  float s0 = 0.f, s1 = 0.f, den = 0.f;
  for (int c = 0; c < na; ++c) {
    const size_t o = ((size_t)(b * nc + c) * H_ + h) * 2;
    const float e = exp2f((ml[o] - M) * LOG2E);
    den += ml[o + 1] * e;
    const float* p = po + ((size_t)(b * nc + c) * H_ + h) * DN;
    s0 += p[tid] * e;
    s1 += p[tid + 256] * e;
  }
  const float inv = 1.f / den;
  float* op = out + ((size_t)b * H_ + h) * DN;
  op[tid]       = s0 * inv;
  op[tid + 256] = s1 * inv;
}

extern "C" void kernel_launch(void* const* d_in, const int* in_sizes, int n_in,
                              void* d_out, int out_size, void* d_ws, size_t ws_size,
                              hipStream_t stream) {
  const float* qn  = (const float*)d_in[0];
  const float* qr  = (const float*)d_in[1];
  const float* kvn = (const float*)d_in[2];
  const float* kvr = (const float*)d_in[3];
  const int*  btab = (const int*)d_in[4];
  const int*  kseq = (const int*)d_in[6];
  float* out = (float*)d_out;

  // workspace-adaptive chunk count: nc chunks of 4096/nc keys
  int nc = 16;
  while (nc > 1 && ((size_t)B_ * nc * H_ * (DN + 2) * sizeof(float)) > ws_size)
    nc >>= 1;
  const int chunk = MAXKV / nc;

  float* po = (float*)d_ws;                       // [B][nc][H][DN] f32
  float* ml = po + (size_t)B_ * nc * H_ * DN;     // [B][nc][H][2]  f32

  mla_chunk<<<B_ * nc, 256, 0, stream>>>(qn, qr, kvn, kvr, btab, kseq,
                                         po, ml, nc, chunk);
  mla_reduce<<<B_ * H_, 256, 0, stream>>>(po, ml, kseq, out, nc, chunk);
}